// Round 1
// baseline (417.664 us; speedup 1.0000x reference)
//
#include <hip/hip_runtime.h>
#include <math.h>

// Problem constants
#define B_ 256
#define M_ 512
#define D_ 768
#define H_ 8
#define DH_ 96
#define C_ 768

// ---------------------------------------------------------------------------
// Generic fp32 GEMM: out(M,N) = X(M,K) @ W(N,K)^T + bias(N), optional sigmoid.
// BM=BN=64, BK=32, 256 threads, 4x4 micro-tile per thread.
// ---------------------------------------------------------------------------
__global__ __launch_bounds__(256) void gemm_xt(
    const float* __restrict__ X, const float* __restrict__ W,
    const float* __restrict__ bias, float* __restrict__ out,
    int M, int N, int K, int act)
{
    __shared__ float As[32][68];   // [k][m], padded to 68 (16B-aligned rows, spread banks)
    __shared__ float Bs[32][68];   // [k][n]

    const int t  = threadIdx.x;
    const int m0 = blockIdx.x * 64;
    const int n0 = blockIdx.y * 64;
    const int tm = t & 15, tn = t >> 4;
    const int r  = t >> 3, cg = t & 7;

    float acc[4][4] = {};

    for (int kt = 0; kt < K; kt += 32) {
        #pragma unroll
        for (int p = 0; p < 2; ++p) {
            const int mr = p * 32 + r;
            float4 xa = *reinterpret_cast<const float4*>(X + (size_t)(m0 + mr) * K + kt + cg * 4);
            As[cg*4+0][mr] = xa.x; As[cg*4+1][mr] = xa.y;
            As[cg*4+2][mr] = xa.z; As[cg*4+3][mr] = xa.w;
            float4 wb = *reinterpret_cast<const float4*>(W + (size_t)(n0 + mr) * K + kt + cg * 4);
            Bs[cg*4+0][mr] = wb.x; Bs[cg*4+1][mr] = wb.y;
            Bs[cg*4+2][mr] = wb.z; Bs[cg*4+3][mr] = wb.w;
        }
        __syncthreads();
        #pragma unroll
        for (int kk = 0; kk < 32; ++kk) {
            float4 a4 = *reinterpret_cast<const float4*>(&As[kk][tm * 4]);
            float4 b4 = *reinterpret_cast<const float4*>(&Bs[kk][tn * 4]);
            acc[0][0] += a4.x * b4.x; acc[0][1] += a4.x * b4.y; acc[0][2] += a4.x * b4.z; acc[0][3] += a4.x * b4.w;
            acc[1][0] += a4.y * b4.x; acc[1][1] += a4.y * b4.y; acc[1][2] += a4.y * b4.z; acc[1][3] += a4.y * b4.w;
            acc[2][0] += a4.z * b4.x; acc[2][1] += a4.z * b4.y; acc[2][2] += a4.z * b4.z; acc[2][3] += a4.z * b4.w;
            acc[3][0] += a4.w * b4.x; acc[3][1] += a4.w * b4.y; acc[3][2] += a4.w * b4.z; acc[3][3] += a4.w * b4.w;
        }
        __syncthreads();
    }

    #pragma unroll
    for (int i = 0; i < 4; ++i) {
        #pragma unroll
        for (int j = 0; j < 4; ++j) {
            const int mm = m0 + tm * 4 + i;
            const int nn = n0 + tn * 4 + j;
            float v = acc[i][j] + bias[nn];
            if (act) v = 1.0f / (1.0f + expf(-v));
            out[(size_t)mm * N + nn] = v;
        }
    }
}

// ---------------------------------------------------------------------------
// Softmax over 512 values in shared memory (block of 256 threads).
// ---------------------------------------------------------------------------
__device__ __forceinline__ void softmax512(float* s, float* red, int t)
{
    float v = fmaxf(s[t], s[t + 256]);
    red[t] = v; __syncthreads();
    #pragma unroll
    for (int off = 128; off > 0; off >>= 1) {
        if (t < off) red[t] = fmaxf(red[t], red[t + off]);
        __syncthreads();
    }
    const float mx = red[0]; __syncthreads();
    const float e0 = expf(s[t] - mx);
    const float e1 = expf(s[t + 256] - mx);
    s[t] = e0; s[t + 256] = e1;
    red[t] = e0 + e1; __syncthreads();
    #pragma unroll
    for (int off = 128; off > 0; off >>= 1) {
        if (t < off) red[t] += red[t + off];
        __syncthreads();
    }
    const float inv = 1.0f / red[0]; __syncthreads();
    s[t] *= inv; s[t + 256] *= inv;
    __syncthreads();
}

// ---------------------------------------------------------------------------
// Attention: one block per (b, h). Computes scores for BOTH read & write
// queries against shared kh (reads kh once), softmaxes both, produces
// ctx (read path) and per-head write attention (write path).
// qrw: (2B, D) stacked [read_keys; write_keys] @ wq^T + bq
// khvh: (M, 2D) = [kh | vh]
// ---------------------------------------------------------------------------
__global__ __launch_bounds__(256) void attn_kernel(
    const float* __restrict__ qrw, const float* __restrict__ khvh,
    float* __restrict__ ctx, float* __restrict__ attnw)
{
    const int b = blockIdx.x, h = blockIdx.y, t = threadIdx.x;
    __shared__ float qr[DH_], qw[DH_], sr[M_], sw[M_], red[256];
    __shared__ float cpart[2][DH_];

    if (t < DH_)            qr[t]       = qrw[(size_t)b * D_ + h * DH_ + t];
    else if (t < 2 * DH_)   qw[t - DH_] = qrw[(size_t)(B_ + b) * D_ + h * DH_ + (t - DH_)];
    __syncthreads();

    const int g = t >> 4, j = t & 15;
    const float scale = 0.10206207261596577f;  // 1/sqrt(96)
    for (int it = 0; it < 32; ++it) {
        const int m = g + (it << 4);
        const float* kr = khvh + (size_t)m * (2 * D_) + h * DH_;
        float pr = 0.f, pw = 0.f;
        #pragma unroll
        for (int i = 0; i < 6; ++i) {
            const float kv = kr[j * 6 + i];
            pr += qr[j * 6 + i] * kv;
            pw += qw[j * 6 + i] * kv;
        }
        #pragma unroll
        for (int off = 8; off > 0; off >>= 1) {
            pr += __shfl_xor(pr, off, 16);
            pw += __shfl_xor(pw, off, 16);
        }
        if (j == 0) { sr[m] = pr * scale; sw[m] = pw * scale; }
    }
    __syncthreads();

    softmax512(sr, red, t);
    softmax512(sw, red, t);

    // ctx[d] = sum_m sr[m] * vh[m, h*96+d]
    if (t < 192) {
        const int d = t % DH_, half = t / DH_;
        const float* vp = khvh + D_ + h * DH_ + d;
        float acc = 0.f;
        const int mEnd = half * 256 + 256;
        for (int m = half * 256; m < mEnd; ++m)
            acc += sr[m] * vp[(size_t)m * (2 * D_)];
        cpart[half][d] = acc;
    }
    __syncthreads();
    if (t < DH_) ctx[(size_t)b * D_ + h * DH_ + t] = cpart[0][t] + cpart[1][t];

    const size_t base = ((size_t)b * H_ + h) * M_;
    attnw[base + t]       = sw[t];
    attnw[base + 256 + t] = sw[t + 256];
}

// ---------------------------------------------------------------------------
// ww[b,m] = mean_h attnw[b,h,m]
// ---------------------------------------------------------------------------
__global__ __launch_bounds__(256) void ww_mean(
    const float* __restrict__ attnw, float* __restrict__ ww)
{
    const int i = blockIdx.x * 256 + threadIdx.x;   // over B*M
    const int b = i >> 9, m = i & 511;
    float s = 0.f;
    #pragma unroll
    for (int h = 0; h < H_; ++h)
        s += attnw[((size_t)b * H_ + h) * M_ + m];
    ww[i] = s * 0.125f;
}

// ---------------------------------------------------------------------------
// Gates + delta: one block per b.
//   ug = sigmoid([cs, rd] . ug_w + ug_b);  fg likewise
//   delta[b,d] = write_data[b,d]*ug - erase_vec[b,d]*fg
// ---------------------------------------------------------------------------
__global__ __launch_bounds__(256) void gates_delta(
    const float* __restrict__ cs, const float* __restrict__ rd,
    const float* __restrict__ wdta, const float* __restrict__ ev,
    const float* __restrict__ ugw, const float* __restrict__ ugb,
    const float* __restrict__ fgw, const float* __restrict__ fgb,
    float* __restrict__ delta)
{
    const int b = blockIdx.x, t = threadIdx.x;
    __shared__ float red[256];
    __shared__ float gates[2];

    float pu = 0.f, pf = 0.f;
    for (int i = t; i < C_; i += 256) {
        const float c = cs[(size_t)b * C_ + i];
        pu += c * ugw[i];
        pf += c * fgw[i];
    }
    for (int i = t; i < D_; i += 256) {
        const float r = rd[(size_t)b * D_ + i];
        pu += r * ugw[C_ + i];
        pf += r * fgw[C_ + i];
    }
    red[t] = pu; __syncthreads();
    #pragma unroll
    for (int off = 128; off > 0; off >>= 1) {
        if (t < off) red[t] += red[t + off];
        __syncthreads();
    }
    if (t == 0) gates[0] = 1.0f / (1.0f + expf(-(red[0] + ugb[0])));
    __syncthreads();
    red[t] = pf; __syncthreads();
    #pragma unroll
    for (int off = 128; off > 0; off >>= 1) {
        if (t < off) red[t] += red[t + off];
        __syncthreads();
    }
    if (t == 0) gates[1] = 1.0f / (1.0f + expf(-(red[0] + fgb[0])));
    __syncthreads();

    const float ug = gates[0], fg = gates[1];
    for (int d = t; d < D_; d += 256)
        delta[(size_t)b * D_ + d] = wdta[(size_t)b * D_ + d] * ug - ev[(size_t)b * D_ + d] * fg;
}

// ---------------------------------------------------------------------------
// Memory update (the 403 MB writer):
//   out[b,m,d] = mem[m,d] + ww[b,m] * delta[b,d]
// One block per (b, group of 4 m-rows); 192 threads, float4 each.
// ---------------------------------------------------------------------------
__global__ __launch_bounds__(192) void update_mem(
    const float* __restrict__ mem, const float* __restrict__ ww,
    const float* __restrict__ delta, float* __restrict__ out)
{
    const int blk = blockIdx.x;
    const int b   = blk >> 7;          // 128 m-groups per b
    const int m0  = (blk & 127) << 2;  // 4 rows per block
    const int t   = threadIdx.x;       // 0..191 (float4 lane within row)

    const float4 d4 = *reinterpret_cast<const float4*>(delta + (size_t)b * D_ + t * 4);
    const float4* m4 = reinterpret_cast<const float4*>(mem);
    float4* o4 = reinterpret_cast<float4*>(out + (size_t)b * M_ * D_);

    #pragma unroll
    for (int i = 0; i < 4; ++i) {
        const int m = m0 + i;
        const float w = ww[(size_t)b * M_ + m];
        float4 mm = m4[(size_t)m * 192 + t];
        float4 r;
        r.x = mm.x + w * d4.x;
        r.y = mm.y + w * d4.y;
        r.z = mm.z + w * d4.z;
        r.w = mm.w + w * d4.w;
        o4[(size_t)m * 192 + t] = r;
    }
}

// ---------------------------------------------------------------------------
extern "C" void kernel_launch(void* const* d_in, const int* in_sizes, int n_in,
                              void* d_out, int out_size, void* d_ws, size_t ws_size,
                              hipStream_t stream)
{
    const float* cs   = (const float*)d_in[0];   // (B, C)
    const float* wdta = (const float*)d_in[1];   // (B, D)
    const float* mem  = (const float*)d_in[2];   // (M, D)
    const float* ipw  = (const float*)d_in[3];   // (3D, D)
    const float* ipb  = (const float*)d_in[4];   // (3D,)
    const float* outw = (const float*)d_in[5];   // (D, D)
    const float* outb = (const float*)d_in[6];   // (D,)
    const float* rw   = (const float*)d_in[7];   // (D, C)
    const float* rb   = (const float*)d_in[8];
    const float* ww_w = (const float*)d_in[9];
    const float* ww_b = (const float*)d_in[10];
    const float* ew   = (const float*)d_in[11];
    const float* eb   = (const float*)d_in[12];
    const float* ugw  = (const float*)d_in[13];
    const float* ugb  = (const float*)d_in[14];
    const float* fgw  = (const float*)d_in[15];
    const float* fgb  = (const float*)d_in[16];

    float* ws = (float*)d_ws;
    float* rwkeys = ws;                       // (2B, D)   = 393216
    float* qrw    = rwkeys + 2 * B_ * D_;     // (2B, D)   = 393216
    float* erase  = qrw + 2 * B_ * D_;        // (B, D)    = 196608
    float* khvh   = erase + B_ * D_;          // (M, 2D)   = 786432
    float* ctx    = khvh + M_ * 2 * D_;       // (B, D)    = 196608
    float* attnw  = ctx + B_ * D_;            // (B, H, M) = 1048576
    float* wwb    = attnw + B_ * H_ * M_;     // (B, M)    = 131072
    float* delta  = wwb + B_ * M_;            // (B, D)    = 196608

    float* rd_out  = (float*)d_out;                 // read_data (B, D)
    float* mem_out = (float*)d_out + B_ * D_;       // updated_memory (B, M, D)

    // kh|vh = memory @ [wk; wv]^T + [bk; bv]    (M, 1536)
    gemm_xt<<<dim3(8, 24), 256, 0, stream>>>(mem, ipw + D_ * D_, ipb + D_, khvh, M_, 2 * D_, D_, 0);
    // read/write keys + erase vector from controller state
    gemm_xt<<<dim3(4, 12), 256, 0, stream>>>(cs, rw,   rb,   rwkeys,            B_, D_, C_, 0);
    gemm_xt<<<dim3(4, 12), 256, 0, stream>>>(cs, ww_w, ww_b, rwkeys + B_ * D_,  B_, D_, C_, 0);
    gemm_xt<<<dim3(4, 12), 256, 0, stream>>>(cs, ew,   eb,   erase,             B_, D_, C_, 1);
    // q projection of stacked [read_keys; write_keys] with shared wq
    gemm_xt<<<dim3(8, 12), 256, 0, stream>>>(rwkeys, ipw, ipb, qrw, 2 * B_, D_, D_, 0);
    // attention (both paths share kh reads)
    attn_kernel<<<dim3(B_, H_), 256, 0, stream>>>(qrw, khvh, ctx, attnw);
    // read_data = ctx @ out_w^T + out_b  -> straight into d_out
    gemm_xt<<<dim3(4, 12), 256, 0, stream>>>(ctx, outw, outb, rd_out, B_, D_, D_, 0);
    // ww = mean over heads
    ww_mean<<<(B_ * M_) / 256, 256, 0, stream>>>(attnw, wwb);
    // gates + delta
    gates_delta<<<B_, 256, 0, stream>>>(cs, rd_out, wdta, erase, ugw, ugb, fgw, fgb, delta);
    // big write: updated_memory
    update_mem<<<B_ * (M_ / 4), 192, 0, stream>>>(mem, wwb, delta, mem_out);
}

// Round 3
// 244.797 us; speedup vs baseline: 1.7062x; 1.7062x over previous
//
#include <hip/hip_runtime.h>
#include <math.h>

// Problem constants
#define B_ 256
#define M_ 512
#define D_ 768
#define H_ 8
#define DH_ 96
#define C_ 768

typedef float f32x4_t __attribute__((ext_vector_type(4)));

// ---------------------------------------------------------------------------
// fp32 GEMM tile (64x64, K=768 fixed), software-pipelined global->LDS.
// out(M,N) = X(M,K) @ W(N,K)^T + bias(N), optional sigmoid.
// ---------------------------------------------------------------------------
__device__ __forceinline__ void gemm_tile_k768(
    const float* __restrict__ X, const float* __restrict__ W,
    const float* __restrict__ bias, float* __restrict__ out,
    int N, int m0, int n0, int act,
    float (*As)[68], float (*Bs)[68])
{
    const int t  = threadIdx.x;
    const int tm = t & 15, tn = t >> 4;
    const int r  = t >> 3, cg = t & 7;

    float acc[4][4] = {};
    float4 xa[2], wb[2];

    // preload k-tile 0
    #pragma unroll
    for (int p = 0; p < 2; ++p) {
        const int mr = p * 32 + r;
        xa[p] = *reinterpret_cast<const float4*>(X + (size_t)(m0 + mr) * 768 + cg * 4);
        wb[p] = *reinterpret_cast<const float4*>(W + (size_t)(n0 + mr) * 768 + cg * 4);
    }

    for (int kt = 0; kt < 768; kt += 32) {
        #pragma unroll
        for (int p = 0; p < 2; ++p) {
            const int mr = p * 32 + r;
            As[cg*4+0][mr] = xa[p].x; As[cg*4+1][mr] = xa[p].y;
            As[cg*4+2][mr] = xa[p].z; As[cg*4+3][mr] = xa[p].w;
            Bs[cg*4+0][mr] = wb[p].x; Bs[cg*4+1][mr] = wb[p].y;
            Bs[cg*4+2][mr] = wb[p].z; Bs[cg*4+3][mr] = wb[p].w;
        }
        __syncthreads();
        if (kt + 32 < 768) {   // issue next tile's loads; latency hides under FMAs
            #pragma unroll
            for (int p = 0; p < 2; ++p) {
                const int mr = p * 32 + r;
                xa[p] = *reinterpret_cast<const float4*>(X + (size_t)(m0 + mr) * 768 + kt + 32 + cg * 4);
                wb[p] = *reinterpret_cast<const float4*>(W + (size_t)(n0 + mr) * 768 + kt + 32 + cg * 4);
            }
        }
        #pragma unroll
        for (int kk = 0; kk < 32; ++kk) {
            float4 a4 = *reinterpret_cast<const float4*>(&As[kk][tm * 4]);
            float4 b4 = *reinterpret_cast<const float4*>(&Bs[kk][tn * 4]);
            acc[0][0] += a4.x * b4.x; acc[0][1] += a4.x * b4.y; acc[0][2] += a4.x * b4.z; acc[0][3] += a4.x * b4.w;
            acc[1][0] += a4.y * b4.x; acc[1][1] += a4.y * b4.y; acc[1][2] += a4.y * b4.z; acc[1][3] += a4.y * b4.w;
            acc[2][0] += a4.z * b4.x; acc[2][1] += a4.z * b4.y; acc[2][2] += a4.z * b4.z; acc[2][3] += a4.z * b4.w;
            acc[3][0] += a4.w * b4.x; acc[3][1] += a4.w * b4.y; acc[3][2] += a4.w * b4.z; acc[3][3] += a4.w * b4.w;
        }
        __syncthreads();
    }

    const int nn0 = n0 + tn * 4;
    float4 b4 = *reinterpret_cast<const float4*>(bias + nn0);
    #pragma unroll
    for (int i = 0; i < 4; ++i) {
        const int mm = m0 + tm * 4 + i;
        float4 o;
        o.x = acc[i][0] + b4.x; o.y = acc[i][1] + b4.y;
        o.z = acc[i][2] + b4.z; o.w = acc[i][3] + b4.w;
        if (act) {
            o.x = 1.0f / (1.0f + expf(-o.x)); o.y = 1.0f / (1.0f + expf(-o.y));
            o.z = 1.0f / (1.0f + expf(-o.z)); o.w = 1.0f / (1.0f + expf(-o.w));
        }
        *reinterpret_cast<float4*>(out + (size_t)mm * N + nn0) = o;
    }
}

// ---------------------------------------------------------------------------
// Stage 1: all input-independent GEMMs in ONE launch (336 blocks):
//   [0,192):   khvh = memory @ [wk;wv]^T + [bk;bv]    (512 x 1536)
//   [192,240): read keys  = cs @ rw^T + rb            (256 x 768)
//   [240,288): write keys = cs @ ww_w^T + ww_b        (256 x 768)
//   [288,336): erase = sigmoid(cs @ ew^T + eb)        (256 x 768)
// ---------------------------------------------------------------------------
__global__ __launch_bounds__(256) void stage1(
    const float* __restrict__ mem, const float* __restrict__ cs,
    const float* __restrict__ ipw, const float* __restrict__ ipb,
    const float* __restrict__ rw, const float* __restrict__ rb,
    const float* __restrict__ ww_w, const float* __restrict__ ww_b,
    const float* __restrict__ ew, const float* __restrict__ eb,
    float* __restrict__ khvh, float* __restrict__ rwkeys, float* __restrict__ erase)
{
    __shared__ float As[32][68];
    __shared__ float Bs[32][68];
    const int bid = blockIdx.x;
    if (bid < 192) {
        gemm_tile_k768(mem, ipw + D_ * D_, ipb + D_, khvh, 2 * D_,
                       (bid / 24) * 64, (bid % 24) * 64, 0, As, Bs);
    } else if (bid < 240) {
        const int l = bid - 192;
        gemm_tile_k768(cs, rw, rb, rwkeys, D_, (l / 12) * 64, (l % 12) * 64, 0, As, Bs);
    } else if (bid < 288) {
        const int l = bid - 240;
        gemm_tile_k768(cs, ww_w, ww_b, rwkeys + B_ * D_, D_, (l / 12) * 64, (l % 12) * 64, 0, As, Bs);
    } else {
        const int l = bid - 288;
        gemm_tile_k768(cs, ew, eb, erase, D_, (l / 12) * 64, (l % 12) * 64, 1, As, Bs);
    }
}

// ---------------------------------------------------------------------------
// Generic single-GEMM launch (used for qrw projection).
// ---------------------------------------------------------------------------
__global__ __launch_bounds__(256) void gemm_k768(
    const float* __restrict__ X, const float* __restrict__ W,
    const float* __restrict__ bias, float* __restrict__ out,
    int N, int ntile_n, int act)
{
    __shared__ float As[32][68];
    __shared__ float Bs[32][68];
    gemm_tile_k768(X, W, bias, out, N,
                   (blockIdx.x / ntile_n) * 64, (blockIdx.x % ntile_n) * 64, act, As, Bs);
}

// ---------------------------------------------------------------------------
// Block softmax over 512 values: wave-level shfl reduce, 4 barriers.
// ---------------------------------------------------------------------------
__device__ __forceinline__ void softmax512f(float* s, volatile float* red4, int t)
{
    float v = fmaxf(s[t], s[t + 256]);
    #pragma unroll
    for (int off = 32; off > 0; off >>= 1) v = fmaxf(v, __shfl_xor(v, off));
    if ((t & 63) == 0) red4[t >> 6] = v;
    __syncthreads();
    const float mx = fmaxf(fmaxf(red4[0], red4[1]), fmaxf(red4[2], red4[3]));
    const float e0 = expf(s[t] - mx);
    const float e1 = expf(s[t + 256] - mx);
    float sum = e0 + e1;
    #pragma unroll
    for (int off = 32; off > 0; off >>= 1) sum += __shfl_xor(sum, off);
    __syncthreads();                 // everyone done reading red4 (max)
    if ((t & 63) == 0) red4[t >> 6] = sum;
    __syncthreads();
    const float inv = 1.0f / (red4[0] + red4[1] + red4[2] + red4[3]);
    s[t] = e0 * inv; s[t + 256] = e1 * inv;
    __syncthreads();
}

// ---------------------------------------------------------------------------
// Attention: one block per (b, h); read & write queries share kh reads.
// ---------------------------------------------------------------------------
__global__ __launch_bounds__(256) void attn_kernel(
    const float* __restrict__ qrw, const float* __restrict__ khvh,
    float* __restrict__ ctx, float* __restrict__ attnw)
{
    const int b = blockIdx.x, h = blockIdx.y, t = threadIdx.x;
    __shared__ float qr[DH_], qw[DH_], sr[M_], sw[M_];
    __shared__ float red4[4];
    __shared__ float cpart[2][DH_];

    if (t < DH_)            qr[t]       = qrw[(size_t)b * D_ + h * DH_ + t];
    else if (t < 2 * DH_)   qw[t - DH_] = qrw[(size_t)(B_ + b) * D_ + h * DH_ + (t - DH_)];
    __syncthreads();

    const int g = t >> 4, j = t & 15;
    const float scale = 0.10206207261596577f;  // 1/sqrt(96)
    for (int it = 0; it < 32; ++it) {
        const int m = g + (it << 4);
        const float* kr = khvh + (size_t)m * (2 * D_) + h * DH_;
        float pr = 0.f, pw = 0.f;
        #pragma unroll
        for (int i = 0; i < 6; ++i) {
            const float kv = kr[j * 6 + i];
            pr += qr[j * 6 + i] * kv;
            pw += qw[j * 6 + i] * kv;
        }
        #pragma unroll
        for (int off = 8; off > 0; off >>= 1) {
            pr += __shfl_xor(pr, off, 16);
            pw += __shfl_xor(pw, off, 16);
        }
        if (j == 0) { sr[m] = pr * scale; sw[m] = pw * scale; }
    }
    __syncthreads();

    softmax512f(sr, red4, t);
    softmax512f(sw, red4, t);

    // ctx[d] = sum_m sr[m] * vh[m, h*96+d]; 4 independent chains
    if (t < 192) {
        const int d = t % DH_, half = t / DH_;
        const float* vp = khvh + D_ + h * DH_ + d;
        const int mb = half * 256;
        float a0 = 0.f, a1 = 0.f, a2 = 0.f, a3 = 0.f;
        for (int m = 0; m < 256; m += 4) {
            a0 += sr[mb + m]     * vp[(size_t)(mb + m)     * (2 * D_)];
            a1 += sr[mb + m + 1] * vp[(size_t)(mb + m + 1) * (2 * D_)];
            a2 += sr[mb + m + 2] * vp[(size_t)(mb + m + 2) * (2 * D_)];
            a3 += sr[mb + m + 3] * vp[(size_t)(mb + m + 3) * (2 * D_)];
        }
        cpart[half][d] = (a0 + a1) + (a2 + a3);
    }
    __syncthreads();
    if (t < DH_) ctx[(size_t)b * D_ + h * DH_ + t] = cpart[0][t] + cpart[1][t];

    const size_t base = ((size_t)b * H_ + h) * M_;
    attnw[base + t]       = sw[t];
    attnw[base + 256 + t] = sw[t + 256];
}

// ---------------------------------------------------------------------------
// Stage 4: out-projection (48 blocks) + head-mean (512 blocks), one launch.
// ---------------------------------------------------------------------------
__global__ __launch_bounds__(256) void stage4(
    const float* __restrict__ ctx, const float* __restrict__ outw,
    const float* __restrict__ outb, float* __restrict__ rd_out,
    const float* __restrict__ attnw, float* __restrict__ ww)
{
    __shared__ float As[32][68];
    __shared__ float Bs[32][68];
    const int bid = blockIdx.x;
    if (bid < 48) {
        gemm_tile_k768(ctx, outw, outb, rd_out, D_, (bid / 12) * 64, (bid % 12) * 64, 0, As, Bs);
    } else {
        const int i = (bid - 48) * 256 + threadIdx.x;   // over B*M
        const int b = i >> 9, m = i & 511;
        float s = 0.f;
        #pragma unroll
        for (int h = 0; h < H_; ++h)
            s += attnw[((size_t)b * H_ + h) * M_ + m];
        ww[i] = s * 0.125f;
    }
}

// ---------------------------------------------------------------------------
// Gates + delta: one block per b.
// ---------------------------------------------------------------------------
__global__ __launch_bounds__(256) void gates_delta(
    const float* __restrict__ cs, const float* __restrict__ rd,
    const float* __restrict__ wdta, const float* __restrict__ ev,
    const float* __restrict__ ugw, const float* __restrict__ ugb,
    const float* __restrict__ fgw, const float* __restrict__ fgb,
    float* __restrict__ delta)
{
    const int b = blockIdx.x, t = threadIdx.x;
    __shared__ float red4[4];
    __shared__ float gates[2];

    float pu = 0.f, pf = 0.f;
    for (int i = t; i < C_; i += 256) {
        const float c = cs[(size_t)b * C_ + i];
        pu += c * ugw[i];
        pf += c * fgw[i];
    }
    for (int i = t; i < D_; i += 256) {
        const float r = rd[(size_t)b * D_ + i];
        pu += r * ugw[C_ + i];
        pf += r * fgw[C_ + i];
    }
    #pragma unroll
    for (int off = 32; off > 0; off >>= 1) pu += __shfl_xor(pu, off);
    if ((t & 63) == 0) red4[t >> 6] = pu;
    __syncthreads();
    if (t == 0) gates[0] = 1.0f / (1.0f + expf(-(red4[0] + red4[1] + red4[2] + red4[3] + ugb[0])));
    __syncthreads();
    #pragma unroll
    for (int off = 32; off > 0; off >>= 1) pf += __shfl_xor(pf, off);
    if ((t & 63) == 0) red4[t >> 6] = pf;
    __syncthreads();
    if (t == 0) gates[1] = 1.0f / (1.0f + expf(-(red4[0] + red4[1] + red4[2] + red4[3] + fgb[0])));
    __syncthreads();

    const float ug = gates[0], fg = gates[1];
    for (int d = t; d < D_; d += 256)
        delta[(size_t)b * D_ + d] = wdta[(size_t)b * D_ + d] * ug - ev[(size_t)b * D_ + d] * fg;
}

// ---------------------------------------------------------------------------
// Memory update (403 MB writer): out[b,m,d] = mem[m,d] + ww[b,m] * delta[b,d]
// Nontemporal stores via ext_vector_type (builtin rejects HIP_vector_type).
// ---------------------------------------------------------------------------
__global__ __launch_bounds__(192) void update_mem(
    const float* __restrict__ mem, const float* __restrict__ ww,
    const float* __restrict__ delta, float* __restrict__ out)
{
    const int blk = blockIdx.x;
    const int b   = blk >> 7;          // 128 m-groups per b
    const int m0  = (blk & 127) << 2;  // 4 rows per block
    const int t   = threadIdx.x;       // 0..191 (float4 lane within row)

    const f32x4_t d4 = *reinterpret_cast<const f32x4_t*>(delta + (size_t)b * D_ + t * 4);
    const f32x4_t* m4 = reinterpret_cast<const f32x4_t*>(mem);
    f32x4_t* o4 = reinterpret_cast<f32x4_t*>(out + (size_t)b * M_ * D_);

    #pragma unroll
    for (int i = 0; i < 4; ++i) {
        const int m = m0 + i;
        const float w = ww[(size_t)b * M_ + m];
        f32x4_t mm = m4[(size_t)m * 192 + t];
        f32x4_t r = mm + w * d4;
        __builtin_nontemporal_store(r, &o4[(size_t)m * 192 + t]);
    }
}

// ---------------------------------------------------------------------------
extern "C" void kernel_launch(void* const* d_in, const int* in_sizes, int n_in,
                              void* d_out, int out_size, void* d_ws, size_t ws_size,
                              hipStream_t stream)
{
    const float* cs   = (const float*)d_in[0];   // (B, C)
    const float* wdta = (const float*)d_in[1];   // (B, D)
    const float* mem  = (const float*)d_in[2];   // (M, D)
    const float* ipw  = (const float*)d_in[3];   // (3D, D)
    const float* ipb  = (const float*)d_in[4];   // (3D,)
    const float* outw = (const float*)d_in[5];   // (D, D)
    const float* outb = (const float*)d_in[6];   // (D,)
    const float* rw   = (const float*)d_in[7];   // (D, C)
    const float* rb   = (const float*)d_in[8];
    const float* ww_w = (const float*)d_in[9];
    const float* ww_b = (const float*)d_in[10];
    const float* ew   = (const float*)d_in[11];
    const float* eb   = (const float*)d_in[12];
    const float* ugw  = (const float*)d_in[13];
    const float* ugb  = (const float*)d_in[14];
    const float* fgw  = (const float*)d_in[15];
    const float* fgb  = (const float*)d_in[16];

    float* ws = (float*)d_ws;
    float* rwkeys = ws;                       // (2B, D)
    float* qrw    = rwkeys + 2 * B_ * D_;     // (2B, D)
    float* erase  = qrw + 2 * B_ * D_;        // (B, D)
    float* khvh   = erase + B_ * D_;          // (M, 2D)
    float* ctx    = khvh + M_ * 2 * D_;       // (B, D)
    float* attnw  = ctx + B_ * D_;            // (B, H, M)
    float* wwb    = attnw + B_ * H_ * M_;     // (B, M)
    float* delta  = wwb + B_ * M_;            // (B, D)

    float* rd_out  = (float*)d_out;                 // read_data (B, D)
    float* mem_out = (float*)d_out + B_ * D_;       // updated_memory (B, M, D)

    // 1: khvh + read/write keys + erase (all independent, one launch)
    stage1<<<336, 256, 0, stream>>>(mem, cs, ipw, ipb, rw, rb, ww_w, ww_b, ew, eb,
                                    khvh, rwkeys, erase);
    // 2: q projection of stacked [read_keys; write_keys]
    gemm_k768<<<96, 256, 0, stream>>>(rwkeys, ipw, ipb, qrw, D_, 12, 0);
    // 3: attention (read ctx + write attn weights)
    attn_kernel<<<dim3(B_, H_), 256, 0, stream>>>(qrw, khvh, ctx, attnw);
    // 4: out-projection -> d_out, plus head-mean -> ww
    stage4<<<560, 256, 0, stream>>>(ctx, outw, outb, rd_out, attnw, wwb);
    // 5: gates + delta
    gates_delta<<<B_, 256, 0, stream>>>(cs, rd_out, wdta, erase, ugw, ugb, fgw, fgb, delta);
    // 6: big write: updated_memory
    update_mem<<<B_ * (M_ / 4), 192, 0, stream>>>(mem, wwb, delta, mem_out);
}

// Round 4
// 191.424 us; speedup vs baseline: 2.1819x; 1.2788x over previous
//
#include <hip/hip_runtime.h>
#include <math.h>

// Problem constants
#define B_ 256
#define M_ 512
#define D_ 768
#define H_ 8
#define DH_ 96
#define C_ 768

typedef float  f32x4_t __attribute__((ext_vector_type(4)));
typedef short  s16x8   __attribute__((ext_vector_type(8)));
typedef unsigned short u16;

__device__ __forceinline__ u16 cvt_bf16(float f) {
    union { float f; unsigned int u; } v; v.f = f;
    unsigned int r = (v.u + 0x7FFFu + ((v.u >> 16) & 1u)) >> 16;
    return (u16)r;
}
__device__ __forceinline__ float bf16_f32(u16 h) {
    union { unsigned int u; float f; } v; v.u = ((unsigned int)h) << 16;
    return v.f;
}

// ---------------------------------------------------------------------------
// 64x64 MFMA GEMM core. out-tile = A(64xK) @ B(64xK)^T  (both K-major rows).
// A/B staged into LDS as bf16 [kb][row][8] (8KB each), converted from f32
// in registers when the source is f32. 4 waves, wave w owns rows w*16..+15.
// Per k-step(32): 1 A-frag + nfrag B-frags + nfrag MFMAs per wave.
// ---------------------------------------------------------------------------
template<bool ABF16, bool BBF16>
__device__ __forceinline__ void mm64(
    const void* Asrc_, int lda, const void* Bsrc_, int ldb,
    int ksteps, int bRowMax, u16* lA, u16* lB, f32x4_t* acc, int nfrag)
{
    const int t   = threadIdx.x;
    const int row = t & 63, kb = t >> 6;      // staging role
    const int l   = t & 63, w  = t >> 6;      // compute role

    for (int ks = 0; ks < ksteps; ++ks) {
        const int koff = ks * 32 + kb * 8;
        s16x8 va, vb;
        if (ABF16) {
            va = *reinterpret_cast<const s16x8*>((const u16*)Asrc_ + (size_t)row * lda + koff);
        } else {
            const float* p = (const float*)Asrc_ + (size_t)row * lda + koff;
            float4 x = *reinterpret_cast<const float4*>(p);
            float4 y = *reinterpret_cast<const float4*>(p + 4);
            va[0]=cvt_bf16(x.x); va[1]=cvt_bf16(x.y); va[2]=cvt_bf16(x.z); va[3]=cvt_bf16(x.w);
            va[4]=cvt_bf16(y.x); va[5]=cvt_bf16(y.y); va[6]=cvt_bf16(y.z); va[7]=cvt_bf16(y.w);
        }
        const int brow = row < bRowMax ? row : bRowMax;
        if (BBF16) {
            vb = *reinterpret_cast<const s16x8*>((const u16*)Bsrc_ + (size_t)brow * ldb + koff);
        } else {
            const float* p = (const float*)Bsrc_ + (size_t)brow * ldb + koff;
            float4 x = *reinterpret_cast<const float4*>(p);
            float4 y = *reinterpret_cast<const float4*>(p + 4);
            vb[0]=cvt_bf16(x.x); vb[1]=cvt_bf16(x.y); vb[2]=cvt_bf16(x.z); vb[3]=cvt_bf16(x.w);
            vb[4]=cvt_bf16(y.x); vb[5]=cvt_bf16(y.y); vb[6]=cvt_bf16(y.z); vb[7]=cvt_bf16(y.w);
        }
        __syncthreads();   // previous iteration's frag reads complete
        *reinterpret_cast<s16x8*>(lA + t * 8) = va;   // index (kb*64+row)*8 == t*8
        *reinterpret_cast<s16x8*>(lB + t * 8) = vb;
        __syncthreads();
        // A-frag: row = w*16 + (l&15), k = (l>>4)*8 + j
        s16x8 af = *reinterpret_cast<const s16x8*>(lA + (l >> 4) * 512 + (w * 16 + (l & 15)) * 8);
        #pragma unroll
        for (int nb = 0; nb < 4; ++nb) {
            if (nb < nfrag) {
                s16x8 bf = *reinterpret_cast<const s16x8*>(lB + (l >> 4) * 512 + (nb * 16 + (l & 15)) * 8);
                acc[nb] = __builtin_amdgcn_mfma_f32_16x16x32_bf16(af, bf, acc[nb], 0, 0, 0);
            }
        }
    }
}

// C/D layout (m89-verified): col = lane&15, row = (lane>>4)*4 + reg.
__device__ __forceinline__ void epilogue_f32(
    const f32x4_t* acc, float* out, int ldo, int m0, int n0,
    const float* bias, int act, float scale, int nfrag)
{
    const int t = threadIdx.x, l = t & 63, w = t >> 6;
    const int mbase = m0 + w * 16 + (l >> 4) * 4;
    #pragma unroll
    for (int nb = 0; nb < 4; ++nb) {
        if (nb >= nfrag) break;
        const int col = n0 + nb * 16 + (l & 15);
        const float bv = bias ? bias[col] : 0.0f;
        #pragma unroll
        for (int r = 0; r < 4; ++r) {
            float v = acc[nb][r] * scale + bv;
            if (act) v = 1.0f / (1.0f + expf(-v));
            out[(size_t)(mbase + r) * ldo + col] = v;
        }
    }
}

__device__ __forceinline__ void epilogue_bf16s(
    const f32x4_t* acc, u16* out, int ldo, int m0, int n0, float scale, int nfrag)
{
    const int t = threadIdx.x, l = t & 63, w = t >> 6;
    const int mbase = m0 + w * 16 + (l >> 4) * 4;
    #pragma unroll
    for (int nb = 0; nb < 4; ++nb) {
        if (nb >= nfrag) break;
        const int col = n0 + nb * 16 + (l & 15);
        #pragma unroll
        for (int r = 0; r < 4; ++r)
            out[(size_t)(mbase + r) * ldo + col] = cvt_bf16(acc[nb][r] * scale);
    }
}

#define ACC_INIT {{0,0,0,0},{0,0,0,0},{0,0,0,0},{0,0,0,0}}

// ---------------------------------------------------------------------------
// Stage 1 (336 blocks): khvh(512x1536,K768) + read/write keys + erase (sigmoid)
// ---------------------------------------------------------------------------
__global__ __launch_bounds__(256) void stage1_mfma(
    const float* __restrict__ mem, const float* __restrict__ cs,
    const float* __restrict__ ipw, const float* __restrict__ ipb,
    const float* __restrict__ rw, const float* __restrict__ rb,
    const float* __restrict__ ww_w, const float* __restrict__ ww_b,
    const float* __restrict__ ew, const float* __restrict__ eb,
    float* __restrict__ khvh, float* __restrict__ rwkeys, float* __restrict__ erase)
{
    __shared__ u16 lA[4096], lB[4096];
    f32x4_t acc[4] = ACC_INIT;
    const int bid = blockIdx.x;
    if (bid < 192) {
        const int mt = bid / 24, nt = bid % 24;
        mm64<false,false>(mem + (size_t)mt*64*768, 768, ipw + (size_t)768*768 + (size_t)nt*64*768, 768,
                          24, 63, lA, lB, acc, 4);
        epilogue_f32(acc, khvh, 1536, mt*64, nt*64, ipb + 768, 0, 1.0f, 4);
    } else if (bid < 240) {
        const int lid = bid - 192, mt = lid / 12, nt = lid % 12;
        mm64<false,false>(cs + (size_t)mt*64*768, 768, rw + (size_t)nt*64*768, 768, 24, 63, lA, lB, acc, 4);
        epilogue_f32(acc, rwkeys, 768, mt*64, nt*64, rb, 0, 1.0f, 4);
    } else if (bid < 288) {
        const int lid = bid - 240, mt = lid / 12, nt = lid % 12;
        mm64<false,false>(cs + (size_t)mt*64*768, 768, ww_w + (size_t)nt*64*768, 768, 24, 63, lA, lB, acc, 4);
        epilogue_f32(acc, rwkeys + 256*768, 768, mt*64, nt*64, ww_b, 0, 1.0f, 4);
    } else {
        const int lid = bid - 288, mt = lid / 12, nt = lid % 12;
        mm64<false,false>(cs + (size_t)mt*64*768, 768, ew + (size_t)nt*64*768, 768, 24, 63, lA, lB, acc, 4);
        epilogue_f32(acc, erase, 768, mt*64, nt*64, eb, 1, 1.0f, 4);
    }
}

// ---------------------------------------------------------------------------
// vh part of khvh -> vhT[h][d][m] bf16 (for PV B-operand, k(=m)-major)
// ---------------------------------------------------------------------------
__global__ __launch_bounds__(256) void transpose_vh(
    const float* __restrict__ khvh, u16* __restrict__ vhT)
{
    const int d = blockIdx.x, h = blockIdx.y, t = threadIdx.x;
    const float v0 = khvh[(size_t)t * 1536 + 768 + h * 96 + d];
    const float v1 = khvh[(size_t)(t + 256) * 1536 + 768 + h * 96 + d];
    u16* dst = vhT + ((size_t)h * 96 + d) * 512;
    dst[t] = cvt_bf16(v0); dst[t + 256] = cvt_bf16(v1);
}

// ---------------------------------------------------------------------------
// Stage 2 (96 blocks): qrw = rwkeys(512x768) @ wq^T + bq
// ---------------------------------------------------------------------------
__global__ __launch_bounds__(256) void stage2_mfma(
    const float* __restrict__ rwkeys, const float* __restrict__ ipw,
    const float* __restrict__ ipb, float* __restrict__ qrw)
{
    __shared__ u16 lA[4096], lB[4096];
    f32x4_t acc[4] = ACC_INIT;
    const int mt = blockIdx.x / 12, nt = blockIdx.x % 12;
    mm64<false,false>(rwkeys + (size_t)mt*64*768, 768, ipw + (size_t)nt*64*768, 768, 24, 63, lA, lB, acc, 4);
    epilogue_f32(acc, qrw, 768, mt*64, nt*64, ipb, 0, 1.0f, 4);
}

// ---------------------------------------------------------------------------
// Scores (512 blocks, grid(64,8)): S[h] = qrw_h(512x96) @ kh_h^T * scale, bf16 out
// ---------------------------------------------------------------------------
__global__ __launch_bounds__(256) void scores_mfma(
    const float* __restrict__ qrw, const float* __restrict__ khvh, u16* __restrict__ S)
{
    __shared__ u16 lA[4096], lB[4096];
    f32x4_t acc[4] = ACC_INIT;
    const int h = blockIdx.y;
    const int mt = blockIdx.x >> 3, nt = blockIdx.x & 7;
    mm64<false,false>(qrw + (size_t)mt*64*768 + h*96, 768,
                      khvh + (size_t)nt*64*1536 + h*96, 1536, 3, 63, lA, lB, acc, 4);
    epilogue_bf16s(acc, S + (size_t)h*512*512, 512, mt*64, nt*64, 0.10206207261596577f, 4);
}

// ---------------------------------------------------------------------------
// Row softmax (4096 blocks): rid = h*512+q. q<256 -> Pr bf16; else attnw f32.
// ---------------------------------------------------------------------------
__global__ __launch_bounds__(256) void softmax_rows(
    const u16* __restrict__ S, u16* __restrict__ Pr, float* __restrict__ attnw)
{
    const int rid = blockIdx.x, h = rid >> 9, q = rid & 511, t = threadIdx.x;
    __shared__ float red4[4];
    const u16* s = S + (size_t)rid * 512;
    const float s0 = bf16_f32(s[t]), s1 = bf16_f32(s[t + 256]);
    float v = fmaxf(s0, s1);
    #pragma unroll
    for (int off = 32; off > 0; off >>= 1) v = fmaxf(v, __shfl_xor(v, off));
    if ((t & 63) == 0) red4[t >> 6] = v;
    __syncthreads();
    const float mx = fmaxf(fmaxf(red4[0], red4[1]), fmaxf(red4[2], red4[3]));
    float e0 = expf(s0 - mx), e1 = expf(s1 - mx);
    float sum = e0 + e1;
    #pragma unroll
    for (int off = 32; off > 0; off >>= 1) sum += __shfl_xor(sum, off);
    __syncthreads();
    if ((t & 63) == 0) red4[t >> 6] = sum;
    __syncthreads();
    const float inv = 1.0f / (red4[0] + red4[1] + red4[2] + red4[3]);
    e0 *= inv; e1 *= inv;
    if (q < 256) {
        u16* p = Pr + ((size_t)(h * 256 + q)) * 512;
        p[t] = cvt_bf16(e0); p[t + 256] = cvt_bf16(e1);
    } else {
        float* a = attnw + ((size_t)(q - 256) * 8 + h) * 512;
        a[t] = e0; a[t + 256] = e1;
    }
}

// ---------------------------------------------------------------------------
// PV (grid(4,2,8)): ctx_h = Pr_h(256x512) @ vhT_h^T (96x512 k-major)
// ---------------------------------------------------------------------------
__global__ __launch_bounds__(256) void pv_mfma(
    const u16* __restrict__ Pr, const u16* __restrict__ vhT, float* __restrict__ ctx)
{
    __shared__ u16 lA[4096], lB[4096];
    f32x4_t acc[4] = ACC_INIT;
    const int h = blockIdx.z, mt = blockIdx.x, nt = blockIdx.y;
    const int n0 = nt * 64;
    const int nfrag = nt == 0 ? 4 : 2;        // N=96: second tile covers cols 64..95
    const int bmax  = nt == 0 ? 63 : 31;      // clamp staging rows beyond d=95
    mm64<true,true>(Pr + ((size_t)h * 256 + mt * 64) * 512, 512,
                    vhT + ((size_t)h * 96 + n0) * 512, 512, 16, bmax, lA, lB, acc, nfrag);
    epilogue_f32(acc, ctx + h * 96, 768, mt * 64, n0, nullptr, 0, 1.0f, nfrag);
}

// ---------------------------------------------------------------------------
// Stage 4 (560 blocks): out-projection (48) + head-mean ww (512)
// ---------------------------------------------------------------------------
__global__ __launch_bounds__(256) void stage4_mfma(
    const float* __restrict__ ctx, const float* __restrict__ outw,
    const float* __restrict__ outb, float* __restrict__ rd_out,
    const float* __restrict__ attnw, float* __restrict__ ww)
{
    __shared__ u16 lA[4096], lB[4096];
    const int bid = blockIdx.x;
    if (bid < 48) {
        f32x4_t acc[4] = ACC_INIT;
        const int mt = bid / 12, nt = bid % 12;
        mm64<false,false>(ctx + (size_t)mt*64*768, 768, outw + (size_t)nt*64*768, 768, 24, 63, lA, lB, acc, 4);
        epilogue_f32(acc, rd_out, 768, mt*64, nt*64, outb, 0, 1.0f, 4);
    } else {
        const int i = (bid - 48) * 256 + threadIdx.x;   // over B*M
        const int b = i >> 9, m = i & 511;
        float s = 0.f;
        #pragma unroll
        for (int h = 0; h < H_; ++h)
            s += attnw[((size_t)b * H_ + h) * M_ + m];
        ww[i] = s * 0.125f;
    }
}

// ---------------------------------------------------------------------------
// Gates + delta (f32, precision-critical): one block per b.
// ---------------------------------------------------------------------------
__global__ __launch_bounds__(256) void gates_delta(
    const float* __restrict__ cs, const float* __restrict__ rd,
    const float* __restrict__ wdta, const float* __restrict__ ev,
    const float* __restrict__ ugw, const float* __restrict__ ugb,
    const float* __restrict__ fgw, const float* __restrict__ fgb,
    float* __restrict__ delta)
{
    const int b = blockIdx.x, t = threadIdx.x;
    __shared__ float red4[4];
    __shared__ float gates[2];

    float pu = 0.f, pf = 0.f;
    for (int i = t; i < C_; i += 256) {
        const float c = cs[(size_t)b * C_ + i];
        pu += c * ugw[i];
        pf += c * fgw[i];
    }
    for (int i = t; i < D_; i += 256) {
        const float r = rd[(size_t)b * D_ + i];
        pu += r * ugw[C_ + i];
        pf += r * fgw[C_ + i];
    }
    #pragma unroll
    for (int off = 32; off > 0; off >>= 1) pu += __shfl_xor(pu, off);
    if ((t & 63) == 0) red4[t >> 6] = pu;
    __syncthreads();
    if (t == 0) gates[0] = 1.0f / (1.0f + expf(-(red4[0] + red4[1] + red4[2] + red4[3] + ugb[0])));
    __syncthreads();
    #pragma unroll
    for (int off = 32; off > 0; off >>= 1) pf += __shfl_xor(pf, off);
    if ((t & 63) == 0) red4[t >> 6] = pf;
    __syncthreads();
    if (t == 0) gates[1] = 1.0f / (1.0f + expf(-(red4[0] + red4[1] + red4[2] + red4[3] + fgb[0])));
    __syncthreads();

    const float ug = gates[0], fg = gates[1];
    for (int d = t; d < D_; d += 256)
        delta[(size_t)b * D_ + d] = wdta[(size_t)b * D_ + d] * ug - ev[(size_t)b * D_ + d] * fg;
}

// ---------------------------------------------------------------------------
// Memory update (403 MB writer): out[b,m,d] = mem[m,d] + ww[b,m]*delta[b,d]
// ---------------------------------------------------------------------------
__global__ __launch_bounds__(192) void update_mem(
    const float* __restrict__ mem, const float* __restrict__ ww,
    const float* __restrict__ delta, float* __restrict__ out)
{
    const int blk = blockIdx.x;
    const int b   = blk >> 7;
    const int m0  = (blk & 127) << 2;
    const int t   = threadIdx.x;

    const f32x4_t d4 = *reinterpret_cast<const f32x4_t*>(delta + (size_t)b * D_ + t * 4);
    const f32x4_t* m4 = reinterpret_cast<const f32x4_t*>(mem);
    f32x4_t* o4 = reinterpret_cast<f32x4_t*>(out + (size_t)b * M_ * D_);

    #pragma unroll
    for (int i = 0; i < 4; ++i) {
        const int m = m0 + i;
        const float w = ww[(size_t)b * M_ + m];
        f32x4_t mm = m4[(size_t)m * 192 + t];
        f32x4_t r = mm + w * d4;
        __builtin_nontemporal_store(r, &o4[(size_t)m * 192 + t]);
    }
}

// ---------------------------------------------------------------------------
extern "C" void kernel_launch(void* const* d_in, const int* in_sizes, int n_in,
                              void* d_out, int out_size, void* d_ws, size_t ws_size,
                              hipStream_t stream)
{
    const float* cs   = (const float*)d_in[0];
    const float* wdta = (const float*)d_in[1];
    const float* mem  = (const float*)d_in[2];
    const float* ipw  = (const float*)d_in[3];
    const float* ipb  = (const float*)d_in[4];
    const float* outw = (const float*)d_in[5];
    const float* outb = (const float*)d_in[6];
    const float* rw   = (const float*)d_in[7];
    const float* rb   = (const float*)d_in[8];
    const float* ww_w = (const float*)d_in[9];
    const float* ww_b = (const float*)d_in[10];
    const float* ew   = (const float*)d_in[11];
    const float* eb   = (const float*)d_in[12];
    const float* ugw  = (const float*)d_in[13];
    const float* ugb  = (const float*)d_in[14];
    const float* fgw  = (const float*)d_in[15];
    const float* fgb  = (const float*)d_in[16];

    // Workspace (f32 units). Aliasing is phase-safe:
    //   Pr    aliases rwkeys region (dead after stage2; Pr written in softmax)
    //   attnw aliases qrw+khvh     (dead after scores/transpose; written in softmax)
    float* ws     = (float*)d_ws;
    float* rwkeys = ws;                          // reserve 524288 (rwkeys uses 393216; Pr needs 524288)
    float* qrw    = ws + 524288;                 // 393216
    float* khvh   = qrw + 393216;                // 786432
    u16*   Sb     = (u16*)(khvh + 786432);       // 2,097,152 u16 = 1,048,576 f32
    float* erase  = khvh + 786432 + 1048576;     // 196608
    float* ctx    = erase + 196608;              // 196608
    float* wwb    = ctx + 196608;                // 131072
    float* delta  = wwb + 131072;                // 196608
    u16*   vhT    = (u16*)(delta + 196608);      // 393216 u16 = 196608 f32
    u16*   Pr     = (u16*)rwkeys;                // alias
    float* attnw  = qrw;                         // alias

    float* rd_out  = (float*)d_out;              // read_data (B, D)
    float* mem_out = (float*)d_out + B_ * D_;    // updated_memory (B, M, D)

    stage1_mfma<<<336, 256, 0, stream>>>(mem, cs, ipw, ipb, rw, rb, ww_w, ww_b, ew, eb,
                                         khvh, rwkeys, erase);
    transpose_vh<<<dim3(96, 8), 256, 0, stream>>>(khvh, vhT);
    stage2_mfma<<<96, 256, 0, stream>>>(rwkeys, ipw, ipb, qrw);
    scores_mfma<<<dim3(64, 8), 256, 0, stream>>>(qrw, khvh, Sb);
    softmax_rows<<<4096, 256, 0, stream>>>(Sb, Pr, attnw);
    pv_mfma<<<dim3(4, 2, 8), 256, 0, stream>>>(Pr, vhT, ctx);
    stage4_mfma<<<560, 256, 0, stream>>>(ctx, outw, outb, rd_out, attnw, wwb);
    gates_delta<<<B_, 256, 0, stream>>>(cs, rd_out, wdta, erase, ugw, ugb, fgw, fgb, delta);
    update_mem<<<B_ * (M_ / 4), 192, 0, stream>>>(mem, wwb, delta, mem_out);
}

// Round 5
// 146.516 us; speedup vs baseline: 2.8506x; 1.3065x over previous
//
#include <hip/hip_runtime.h>
#include <math.h>

// Problem constants
#define B_ 256
#define M_ 512
#define D_ 768
#define H_ 8
#define DH_ 96
#define C_ 768

typedef float  f32x4_t __attribute__((ext_vector_type(4)));
typedef short  s16x8   __attribute__((ext_vector_type(8)));
typedef unsigned short u16;

__device__ __forceinline__ u16 cvt_bf16(float f) {
    union { float f; unsigned int u; } v; v.f = f;
    unsigned int r = (v.u + 0x7FFFu + ((v.u >> 16) & 1u)) >> 16;
    return (u16)r;
}
__device__ __forceinline__ float bf16_f32(u16 h) {
    union { unsigned int u; float f; } v; v.u = ((unsigned int)h) << 16;
    return v.f;
}

#define ACC_INIT {{0,0,0,0},{0,0,0,0},{0,0,0,0},{0,0,0,0}}

// ---------------------------------------------------------------------------
// Pre-convert all f32 GEMM operands to bf16 (one pass, memory-bound).
// 2048 elems per block (256 thr x 8).
// ---------------------------------------------------------------------------
__global__ __launch_bounds__(256) void conv_bf16(
    const float* __restrict__ mem, const float* __restrict__ cs,
    const float* __restrict__ ipw, const float* __restrict__ rw,
    const float* __restrict__ www, const float* __restrict__ ew,
    const float* __restrict__ outw,
    u16* __restrict__ memb, u16* __restrict__ csb, u16* __restrict__ ipwb,
    u16* __restrict__ rwb, u16* __restrict__ wwwb, u16* __restrict__ ewb,
    u16* __restrict__ outwb)
{
    const int bid = blockIdx.x;
    const float* src; u16* dst; int base;
    if      (bid < 192)  { src = mem;  dst = memb;  base = bid; }
    else if (bid < 288)  { src = cs;   dst = csb;   base = bid - 192; }
    else if (bid < 1152) { src = ipw;  dst = ipwb;  base = bid - 288; }
    else if (bid < 1440) { src = rw;   dst = rwb;   base = bid - 1152; }
    else if (bid < 1728) { src = www;  dst = wwwb;  base = bid - 1440; }
    else if (bid < 2016) { src = ew;   dst = ewb;   base = bid - 1728; }
    else                 { src = outw; dst = outwb; base = bid - 2016; }
    const size_t i = ((size_t)base * 256 + threadIdx.x) * 8;
    float4 x = *reinterpret_cast<const float4*>(src + i);
    float4 y = *reinterpret_cast<const float4*>(src + i + 4);
    s16x8 o;
    o[0]=cvt_bf16(x.x); o[1]=cvt_bf16(x.y); o[2]=cvt_bf16(x.z); o[3]=cvt_bf16(x.w);
    o[4]=cvt_bf16(y.x); o[5]=cvt_bf16(y.y); o[6]=cvt_bf16(y.z); o[7]=cvt_bf16(y.w);
    *reinterpret_cast<s16x8*>(dst + i) = o;
}

// ---------------------------------------------------------------------------
// 64x64 bf16 MFMA GEMM core: tile = A(64xK) @ B(64xK)^T, both K-major bf16.
// LDS layout [kb][row][8] u16. 4 waves; wave w owns rows w*16..+15.
// BK = 32 or 64. Per k-step: b128 global loads -> ds_write -> frag MFMAs.
// ---------------------------------------------------------------------------
template<int BK>
__device__ __forceinline__ void mm64b(
    const u16* __restrict__ A, int lda, const u16* __restrict__ B, int ldb,
    int ksteps, int bRowClamp, u16* lA, u16* lB, f32x4_t* acc, int nfrag)
{
    constexpr int NL = BK / 32;                    // s16x8 chunks per thread
    const int t = threadIdx.x;
    const int srow = t >> 2, kq = t & 3;           // staging role
    const int l = t & 63, w = t >> 6;              // compute role
    const int brow = srow < bRowClamp ? srow : bRowClamp;

    for (int ks = 0; ks < ksteps; ++ks) {
        s16x8 va[NL], vb[NL];
        #pragma unroll
        for (int c = 0; c < NL; ++c) {
            const int ko = ks * BK + (kq * NL + c) * 8;
            va[c] = *reinterpret_cast<const s16x8*>(A + (size_t)srow * lda + ko);
            vb[c] = *reinterpret_cast<const s16x8*>(B + (size_t)brow * ldb + ko);
        }
        __syncthreads();                           // prev frag reads done
        #pragma unroll
        for (int c = 0; c < NL; ++c) {
            const int kb = kq * NL + c;
            *reinterpret_cast<s16x8*>(lA + (kb * 64 + srow) * 8) = va[c];
            *reinterpret_cast<s16x8*>(lB + (kb * 64 + srow) * 8) = vb[c];
        }
        __syncthreads();
        #pragma unroll
        for (int ksub = 0; ksub < NL; ++ksub) {
            const int kb = (l >> 4) + ksub * 4;
            s16x8 af = *reinterpret_cast<const s16x8*>(lA + (kb * 64 + w * 16 + (l & 15)) * 8);
            #pragma unroll
            for (int nb = 0; nb < 4; ++nb) {
                if (nb < nfrag) {
                    s16x8 bf = *reinterpret_cast<const s16x8*>(lB + (kb * 64 + nb * 16 + (l & 15)) * 8);
                    acc[nb] = __builtin_amdgcn_mfma_f32_16x16x32_bf16(af, bf, acc[nb], 0, 0, 0);
                }
            }
        }
    }
}

// C/D layout (m89-verified): col = lane&15, row = (lane>>4)*4 + reg.
__device__ __forceinline__ void epilogue_f32(
    const f32x4_t* acc, float* out, int ldo, int m0, int n0,
    const float* bias, int act, int nfrag)
{
    const int t = threadIdx.x, l = t & 63, w = t >> 6;
    const int mbase = m0 + w * 16 + (l >> 4) * 4;
    #pragma unroll
    for (int nb = 0; nb < 4; ++nb) {
        if (nb >= nfrag) break;
        const int col = n0 + nb * 16 + (l & 15);
        const float bv = bias ? bias[col] : 0.0f;
        #pragma unroll
        for (int r = 0; r < 4; ++r) {
            float v = acc[nb][r] + bv;
            if (act) v = 1.0f / (1.0f + expf(-v));
            out[(size_t)(mbase + r) * ldo + col] = v;
        }
    }
}

__device__ __forceinline__ void epilogue_bf16(
    const f32x4_t* acc, u16* out, int ldo, int m0, int n0,
    const float* bias, float scale, int nfrag)
{
    const int t = threadIdx.x, l = t & 63, w = t >> 6;
    const int mbase = m0 + w * 16 + (l >> 4) * 4;
    #pragma unroll
    for (int nb = 0; nb < 4; ++nb) {
        if (nb >= nfrag) break;
        const int col = n0 + nb * 16 + (l & 15);
        const float bv = bias ? bias[col] : 0.0f;
        #pragma unroll
        for (int r = 0; r < 4; ++r)
            out[(size_t)(mbase + r) * ldo + col] = cvt_bf16(acc[nb][r] * scale + bv);
    }
}

// ---------------------------------------------------------------------------
// Stage 1 (336 blocks):
//   [0,192):   kh|vh = memory @ [wk;wv]^T + bias -> khb (bf16) + vhT (bf16, transposed)
//   [192,240): read keys  -> rwkeysb rows 0..255 (bf16)
//   [240,288): write keys -> rwkeysb rows 256..511 (bf16)
//   [288,336): erase = sigmoid(...) -> f32
// ---------------------------------------------------------------------------
__global__ __launch_bounds__(256) void stage1_mfma(
    const u16* __restrict__ memb, const u16* __restrict__ csb,
    const u16* __restrict__ ipwb, const float* __restrict__ ipb,
    const u16* __restrict__ rwb, const float* __restrict__ rb,
    const u16* __restrict__ wwwb, const float* __restrict__ ww_b,
    const u16* __restrict__ ewb, const float* __restrict__ eb,
    u16* __restrict__ khb, u16* __restrict__ vhT,
    u16* __restrict__ rwkeysb, float* __restrict__ erase)
{
    __shared__ u16 lA[8192], lB[8192];
    f32x4_t acc[4] = ACC_INIT;
    const int bid = blockIdx.x;
    if (bid < 192) {
        const int mt = bid / 24, nt = bid % 24;
        mm64b<64>(memb + (size_t)mt * 64 * 768, 768,
                  ipwb + (size_t)768 * 768 + (size_t)nt * 64 * 768, 768,
                  12, 63, lA, lB, acc, 4);
        const int t = threadIdx.x, l = t & 63, w = t >> 6;
        const int mbase = mt * 64 + w * 16 + (l >> 4) * 4;
        if (nt < 12) {
            #pragma unroll
            for (int nb = 0; nb < 4; ++nb) {
                const int col = nt * 64 + nb * 16 + (l & 15);
                const float bv = ipb[768 + col];
                #pragma unroll
                for (int r = 0; r < 4; ++r)
                    khb[(size_t)(mbase + r) * 768 + col] = cvt_bf16(acc[nb][r] + bv);
            }
        } else {
            #pragma unroll
            for (int nb = 0; nb < 4; ++nb) {
                const int cg = (nt - 12) * 64 + nb * 16 + (l & 15);   // 0..767
                const int h = cg / 96, d = cg % 96;
                const float bv = ipb[1536 + cg];
                u16* dst = vhT + ((size_t)h * 96 + d) * 512;
                #pragma unroll
                for (int r = 0; r < 4; ++r)
                    dst[mbase + r] = cvt_bf16(acc[nb][r] + bv);
            }
        }
    } else if (bid < 240) {
        const int lid = bid - 192, mt = lid / 12, nt = lid % 12;
        mm64b<64>(csb + (size_t)mt * 64 * 768, 768, rwb + (size_t)nt * 64 * 768, 768,
                  12, 63, lA, lB, acc, 4);
        epilogue_bf16(acc, rwkeysb, 768, mt * 64, nt * 64, rb, 1.0f, 4);
    } else if (bid < 288) {
        const int lid = bid - 240, mt = lid / 12, nt = lid % 12;
        mm64b<64>(csb + (size_t)mt * 64 * 768, 768, wwwb + (size_t)nt * 64 * 768, 768,
                  12, 63, lA, lB, acc, 4);
        epilogue_bf16(acc, rwkeysb + (size_t)256 * 768, 768, mt * 64, nt * 64, ww_b, 1.0f, 4);
    } else {
        const int lid = bid - 288, mt = lid / 12, nt = lid % 12;
        mm64b<64>(csb + (size_t)mt * 64 * 768, 768, ewb + (size_t)nt * 64 * 768, 768,
                  12, 63, lA, lB, acc, 4);
        epilogue_f32(acc, erase, 768, mt * 64, nt * 64, eb, 1, 4);
    }
}

// ---------------------------------------------------------------------------
// Stage 2 (96 blocks): qrw = rwkeys(512x768) @ wq^T + bq -> bf16
// ---------------------------------------------------------------------------
__global__ __launch_bounds__(256) void stage2_mfma(
    const u16* __restrict__ rwkeysb, const u16* __restrict__ ipwb,
    const float* __restrict__ ipb, u16* __restrict__ qrwb)
{
    __shared__ u16 lA[8192], lB[8192];
    f32x4_t acc[4] = ACC_INIT;
    const int mt = blockIdx.x / 12, nt = blockIdx.x % 12;
    mm64b<64>(rwkeysb + (size_t)mt * 64 * 768, 768, ipwb + (size_t)nt * 64 * 768, 768,
              12, 63, lA, lB, acc, 4);
    epilogue_bf16(acc, qrwb, 768, mt * 64, nt * 64, ipb, 1.0f, 4);
}

// ---------------------------------------------------------------------------
// Scores (grid(64,8)): S[h] = qrw_h(512x96) @ kh_h^T * scale -> bf16
// ---------------------------------------------------------------------------
__global__ __launch_bounds__(256) void scores_mfma(
    const u16* __restrict__ qrwb, const u16* __restrict__ khb, u16* __restrict__ S)
{
    __shared__ u16 lA[4096], lB[4096];
    f32x4_t acc[4] = ACC_INIT;
    const int h = blockIdx.y;
    const int mt = blockIdx.x >> 3, nt = blockIdx.x & 7;
    mm64b<32>(qrwb + (size_t)mt * 64 * 768 + h * 96, 768,
              khb + (size_t)nt * 64 * 768 + h * 96, 768, 3, 63, lA, lB, acc, 4);
    epilogue_bf16(acc, S + (size_t)h * 512 * 512, 512, mt * 64, nt * 64,
                  nullptr, 0.10206207261596577f, 4);
}

// ---------------------------------------------------------------------------
// Row softmax (4096 blocks): rid = h*512+q. q<256 -> Pr bf16; else attnw f32.
// ---------------------------------------------------------------------------
__global__ __launch_bounds__(256) void softmax_rows(
    const u16* __restrict__ S, u16* __restrict__ Pr, float* __restrict__ attnw)
{
    const int rid = blockIdx.x, h = rid >> 9, q = rid & 511, t = threadIdx.x;
    __shared__ float red4[4];
    const u16* s = S + (size_t)rid * 512;
    const float s0 = bf16_f32(s[t]), s1 = bf16_f32(s[t + 256]);
    float v = fmaxf(s0, s1);
    #pragma unroll
    for (int off = 32; off > 0; off >>= 1) v = fmaxf(v, __shfl_xor(v, off));
    if ((t & 63) == 0) red4[t >> 6] = v;
    __syncthreads();
    const float mx = fmaxf(fmaxf(red4[0], red4[1]), fmaxf(red4[2], red4[3]));
    float e0 = expf(s0 - mx), e1 = expf(s1 - mx);
    float sum = e0 + e1;
    #pragma unroll
    for (int off = 32; off > 0; off >>= 1) sum += __shfl_xor(sum, off);
    __syncthreads();
    if ((t & 63) == 0) red4[t >> 6] = sum;
    __syncthreads();
    const float inv = 1.0f / (red4[0] + red4[1] + red4[2] + red4[3]);
    e0 *= inv; e1 *= inv;
    if (q < 256) {
        u16* p = Pr + ((size_t)(h * 256 + q)) * 512;
        p[t] = cvt_bf16(e0); p[t + 256] = cvt_bf16(e1);
    } else {
        float* a = attnw + ((size_t)(q - 256) * 8 + h) * 512;
        a[t] = e0; a[t + 256] = e1;
    }
}

// ---------------------------------------------------------------------------
// PV (grid(4,2,8)): ctx_h = Pr_h(256x512) @ vhT_h^T (96x512 k-major) -> bf16
// ---------------------------------------------------------------------------
__global__ __launch_bounds__(256) void pv_mfma(
    const u16* __restrict__ Pr, const u16* __restrict__ vhT, u16* __restrict__ ctxb)
{
    __shared__ u16 lA[8192], lB[8192];
    f32x4_t acc[4] = ACC_INIT;
    const int h = blockIdx.z, mt = blockIdx.x, nt = blockIdx.y;
    const int n0 = nt * 64;
    const int nfrag = nt == 0 ? 4 : 2;        // N=96
    const int bclamp = nt == 0 ? 63 : 31;
    mm64b<64>(Pr + ((size_t)h * 256 + mt * 64) * 512, 512,
              vhT + ((size_t)h * 96 + n0) * 512, 512, 8, bclamp, lA, lB, acc, nfrag);
    epilogue_bf16(acc, ctxb + h * 96, 768, mt * 64, n0, nullptr, 1.0f, nfrag);
}

// ---------------------------------------------------------------------------
// Stage 4 (560 blocks): out-projection (48) -> rd_out f32; head-mean ww (512)
// ---------------------------------------------------------------------------
__global__ __launch_bounds__(256) void stage4_mfma(
    const u16* __restrict__ ctxb, const u16* __restrict__ outwb,
    const float* __restrict__ outb, float* __restrict__ rd_out,
    const float* __restrict__ attnw, float* __restrict__ ww)
{
    __shared__ u16 lA[8192], lB[8192];
    const int bid = blockIdx.x;
    if (bid < 48) {
        f32x4_t acc[4] = ACC_INIT;
        const int mt = bid / 12, nt = bid % 12;
        mm64b<64>(ctxb + (size_t)mt * 64 * 768, 768, outwb + (size_t)nt * 64 * 768, 768,
                  12, 63, lA, lB, acc, 4);
        epilogue_f32(acc, rd_out, 768, mt * 64, nt * 64, outb, 0, 4);
    } else {
        const int i = (bid - 48) * 256 + threadIdx.x;   // over B*M
        const int b = i >> 9, m = i & 511;
        float s = 0.f;
        #pragma unroll
        for (int h = 0; h < H_; ++h)
            s += attnw[((size_t)b * H_ + h) * M_ + m];
        ww[i] = s * 0.125f;
    }
}

// ---------------------------------------------------------------------------
// Gates + delta (f32, precision-critical): one block per b.
// ---------------------------------------------------------------------------
__global__ __launch_bounds__(256) void gates_delta(
    const float* __restrict__ cs, const float* __restrict__ rd,
    const float* __restrict__ wdta, const float* __restrict__ ev,
    const float* __restrict__ ugw, const float* __restrict__ ugb,
    const float* __restrict__ fgw, const float* __restrict__ fgb,
    float* __restrict__ delta)
{
    const int b = blockIdx.x, t = threadIdx.x;
    __shared__ float red4[4];
    __shared__ float gates[2];

    float pu = 0.f, pf = 0.f;
    for (int i = t; i < C_; i += 256) {
        const float c = cs[(size_t)b * C_ + i];
        pu += c * ugw[i];
        pf += c * fgw[i];
    }
    for (int i = t; i < D_; i += 256) {
        const float r = rd[(size_t)b * D_ + i];
        pu += r * ugw[C_ + i];
        pf += r * fgw[C_ + i];
    }
    #pragma unroll
    for (int off = 32; off > 0; off >>= 1) pu += __shfl_xor(pu, off);
    if ((t & 63) == 0) red4[t >> 6] = pu;
    __syncthreads();
    if (t == 0) gates[0] = 1.0f / (1.0f + expf(-(red4[0] + red4[1] + red4[2] + red4[3] + ugb[0])));
    __syncthreads();
    #pragma unroll
    for (int off = 32; off > 0; off >>= 1) pf += __shfl_xor(pf, off);
    if ((t & 63) == 0) red4[t >> 6] = pf;
    __syncthreads();
    if (t == 0) gates[1] = 1.0f / (1.0f + expf(-(red4[0] + red4[1] + red4[2] + red4[3] + fgb[0])));
    __syncthreads();

    const float ug = gates[0], fg = gates[1];
    for (int d = t; d < D_; d += 256)
        delta[(size_t)b * D_ + d] = wdta[(size_t)b * D_ + d] * ug - ev[(size_t)b * D_ + d] * fg;
}

// ---------------------------------------------------------------------------
// Memory update (403 MB writer): out[b,m,d] = mem[m,d] + ww[b,m]*delta[b,d]
// 8 rows per block, NT stores. MUST run last (d_out scratch dies here).
// ---------------------------------------------------------------------------
__global__ __launch_bounds__(192) void update_mem(
    const float* __restrict__ mem, const float* __restrict__ ww,
    const float* __restrict__ delta, float* __restrict__ out)
{
    const int blk = blockIdx.x;
    const int b   = blk >> 6;          // 64 m-groups per b
    const int m0  = (blk & 63) << 3;   // 8 rows per block
    const int t   = threadIdx.x;       // 0..191

    const f32x4_t d4 = *reinterpret_cast<const f32x4_t*>(delta + (size_t)b * D_ + t * 4);
    const f32x4_t* m4 = reinterpret_cast<const f32x4_t*>(mem);
    f32x4_t* o4 = reinterpret_cast<f32x4_t*>(out + (size_t)b * M_ * D_);

    #pragma unroll
    for (int i = 0; i < 8; ++i) {
        const int m = m0 + i;
        const float w = ww[(size_t)b * M_ + m];
        f32x4_t mm = m4[(size_t)m * 192 + t];
        f32x4_t r = mm + w * d4;
        __builtin_nontemporal_store(r, &o4[(size_t)m * 192 + t]);
    }
}

// ---------------------------------------------------------------------------
extern "C" void kernel_launch(void* const* d_in, const int* in_sizes, int n_in,
                              void* d_out, int out_size, void* d_ws, size_t ws_size,
                              hipStream_t stream)
{
    const float* cs   = (const float*)d_in[0];
    const float* wdta = (const float*)d_in[1];
    const float* mem  = (const float*)d_in[2];
    const float* ipw  = (const float*)d_in[3];
    const float* ipb  = (const float*)d_in[4];
    const float* outw = (const float*)d_in[5];
    const float* outb = (const float*)d_in[6];
    const float* rw   = (const float*)d_in[7];
    const float* rb   = (const float*)d_in[8];
    const float* ww_w = (const float*)d_in[9];
    const float* ww_b = (const float*)d_in[10];
    const float* ew   = (const float*)d_in[11];
    const float* eb   = (const float*)d_in[12];
    const float* ugw  = (const float*)d_in[13];
    const float* ugb  = (const float*)d_in[14];
    const float* fgw  = (const float*)d_in[15];
    const float* fgb  = (const float*)d_in[16];

    float* rd_out  = (float*)d_out;              // read_data (B, D)
    float* mem_out = (float*)d_out + B_ * D_;    // updated_memory (B, M, D)

    // Scratch lives in the mem_out region (403 MB, dead until update_mem,
    // which is the last kernel and reads only mem/ww/delta). Offsets in f32 words.
    float* S0 = mem_out;
    u16*   khb     = (u16*)(S0 + 0);        // 512x768 bf16
    u16*   vhT     = (u16*)(S0 + 196608);   // 8x96x512 bf16
    u16*   rwkeysb = (u16*)(S0 + 393216);   // 512x768 bf16
    u16*   qrwb    = (u16*)(S0 + 589824);   // 512x768 bf16
    u16*   Sb      = (u16*)(S0 + 786432);   // 8x512x512 bf16
    u16*   Prb     = (u16*)(S0 + 1835008);  // 8x256x512 bf16
    float* attnw   =        S0 + 2359296;   // 256x8x512 f32
    u16*   ctxb    = (u16*)(S0 + 3407872);  // 256x768 bf16
    float* erase   =        S0 + 3506176;   // 256x768 f32
    u16*   memb    = (u16*)(S0 + 3702784);  // 512x768 bf16
    u16*   csb     = (u16*)(S0 + 3899392);  // 256x768 bf16
    u16*   ipwb    = (u16*)(S0 + 3997696);  // 2304x768 bf16
    u16*   rwb     = (u16*)(S0 + 4882432);  // 768x768 bf16
    u16*   wwwb    = (u16*)(S0 + 5177344);  // 768x768 bf16
    u16*   ewb     = (u16*)(S0 + 5472256);  // 768x768 bf16
    u16*   outwb   = (u16*)(S0 + 5767168);  // 768x768 bf16

    // d_ws: only buffers that must survive into update_mem.
    float* wwb   = (float*)d_ws;             // (B, M)
    float* delta = wwb + B_ * M_;            // (B, D)

    conv_bf16<<<2304, 256, 0, stream>>>(mem, cs, ipw, rw, ww_w, ew, outw,
                                        memb, csb, ipwb, rwb, wwwb, ewb, outwb);
    stage1_mfma<<<336, 256, 0, stream>>>(memb, csb, ipwb, ipb, rwb, rb, wwwb, ww_b,
                                         ewb, eb, khb, vhT, rwkeysb, erase);
    stage2_mfma<<<96, 256, 0, stream>>>(rwkeysb, ipwb, ipb, qrwb);
    scores_mfma<<<dim3(64, 8), 256, 0, stream>>>(qrwb, khb, Sb);
    softmax_rows<<<4096, 256, 0, stream>>>(Sb, Prb, attnw);
    pv_mfma<<<dim3(4, 2, 8), 256, 0, stream>>>(Prb, vhT, ctxb);
    stage4_mfma<<<560, 256, 0, stream>>>(ctxb, outwb, outb, rd_out, attnw, wwb);
    gates_delta<<<B_, 256, 0, stream>>>(cs, rd_out, wdta, erase, ugw, ugb, fgw, fgb, delta);
    update_mem<<<B_ * (M_ / 8), 192, 0, stream>>>(mem, wwb, delta, mem_out);
}